// Round 1
// baseline (463.806 us; speedup 1.0000x reference)
//
#include <hip/hip_runtime.h>
#include <hip/hip_bf16.h>

// MultiHeadSelfAttention: B=4, S=2048, D=1024, H=16, HD=64, fp32 in/out.
// Strategy: cast to bf16 once, then bf16-MFMA GEMMs (m97 128x128 structure)
// + flash attention (4 waves x 64 q-rows, KV tiles of 64 in padded LDS).

#define B_  4
#define S_  2048
#define D_  1024
#define H_  16
#define HD_ 64
#define M_  (B_*S_)   // 8192 rows

typedef __attribute__((ext_vector_type(8))) short short8;   // 8 x bf16 (4 VGPR)
typedef __attribute__((ext_vector_type(4))) float f32x4;    // MFMA acc
typedef __hip_bfloat16 bf16;

// ---------------------------------------------------------------- helpers
__device__ inline void gload_lds16(const void* g, void* l) {
  // async global->LDS, 16B per lane; LDS dest = wave-uniform base + lane*16
  __builtin_amdgcn_global_load_lds(
      (const __attribute__((address_space(1))) void*)g,
      (__attribute__((address_space(3))) void*)l,
      16, 0, 0);
}

__device__ inline f32x4 mfma16(short8 a, short8 b, f32x4 c) {
  return __builtin_amdgcn_mfma_f32_16x16x32_bf16(a, b, c, 0, 0, 0);
}

// ---------------------------------------------------------------- convert x
__global__ void convert_x_kernel(const float* __restrict__ x, bf16* __restrict__ xb) {
  const int i = (blockIdx.x * 256 + threadIdx.x) * 8;   // grid covers exactly M_*D_
  float4 a = *reinterpret_cast<const float4*>(x + i);
  float4 b = *reinterpret_cast<const float4*>(x + i + 4);
  bf16 o[8];
  o[0] = (bf16)a.x; o[1] = (bf16)a.y; o[2] = (bf16)a.z; o[3] = (bf16)a.w;
  o[4] = (bf16)b.x; o[5] = (bf16)b.y; o[6] = (bf16)b.z; o[7] = (bf16)b.w;
  *reinterpret_cast<int4*>(xb + i) = *reinterpret_cast<const int4*>(o);
}

// ------------------------------------------------- transpose + convert weights
struct TP { const float* w[4]; bf16* wt[4]; };

__global__ void transpose_w_kernel(TP p) {
  const float* w = p.w[blockIdx.z];
  bf16* wt = p.wt[blockIdx.z];
  __shared__ float t[32][33];
  const int k0 = blockIdx.y * 32, n0 = blockIdx.x * 32;
  const int c = threadIdx.x & 31, r4 = threadIdx.x >> 5;
  #pragma unroll
  for (int i = 0; i < 4; ++i) {
    int r = r4 + i * 8;
    t[r][c] = w[(size_t)(k0 + r) * D_ + n0 + c];
  }
  __syncthreads();
  #pragma unroll
  for (int i = 0; i < 4; ++i) {
    int r = r4 + i * 8;
    wt[(size_t)(n0 + r) * D_ + k0 + c] = (bf16)t[c][r];
  }
}

// ---------------------------------------------------------------- GEMM
// C[M,N] = A[M,K] @ Bt[N,K]^T + bias, 128x128 tile, BK=32, 4 waves (2x2),
// each wave 64x64 = 4x4 fragments of 16x16x32 MFMA.
// MODE 0: bf16 out, head-split [bh][s][hd]   (q / k)
// MODE 1: bf16 out, head-split T [bh][hd][s] (v transposed)
// MODE 2: fp32 out, plain [r][c]             (final projection)
template<int MODE>
__global__ __launch_bounds__(256) void gemm_kernel(
    const bf16* __restrict__ A, const bf16* __restrict__ Bt,
    const float* __restrict__ bias, void* __restrict__ out, float alpha)
{
  constexpr int BK = 32;
  __shared__ __align__(16) bf16 As[128 * BK];
  __shared__ __align__(16) bf16 Bs[128 * BK];
  const int tid = threadIdx.x;
  const int w = tid >> 6, l = tid & 63;
  const int lo = l & 15, hi = l >> 4;
  const int wm = w >> 1, wn = w & 1;
  const int row0 = blockIdx.y * 128;
  const int col0 = blockIdx.x * 128;

  f32x4 acc[4][4] = {};

  for (int kt = 0; kt < D_; kt += BK) {
    __syncthreads();
    #pragma unroll
    for (int i = 0; i < 2; ++i) {
      const int cb = i * 256 + w * 64;      // wave-uniform chunk base
      const int c  = cb + l;                // this lane's 16B chunk
      // chunk c -> tile row c>>2, col (c&3)*8 ; LDS linear offset c*8 elems
      gload_lds16(A  + (size_t)(row0 + (c >> 2)) * D_ + kt + (c & 3) * 8,
                  (void*)(As + cb * 8));
      gload_lds16(Bt + (size_t)(col0 + (c >> 2)) * D_ + kt + (c & 3) * 8,
                  (void*)(Bs + cb * 8));
    }
    __syncthreads();

    short8 a[4], b[4];
    #pragma unroll
    for (int m = 0; m < 4; ++m)
      a[m] = *reinterpret_cast<const short8*>(As + (wm*64 + m*16 + lo) * BK + hi*8);
    #pragma unroll
    for (int n = 0; n < 4; ++n)
      b[n] = *reinterpret_cast<const short8*>(Bs + (wn*64 + n*16 + lo) * BK + hi*8);
    #pragma unroll
    for (int m = 0; m < 4; ++m)
      #pragma unroll
      for (int n = 0; n < 4; ++n)
        acc[m][n] = mfma16(a[m], b[n], acc[m][n]);
  }

  // epilogue: C/D layout col = lane&15, row = (lane>>4)*4 + j
  #pragma unroll
  for (int n = 0; n < 4; ++n) {
    const int c = col0 + wn*64 + n*16 + lo;
    const float bv = bias[c];
    #pragma unroll
    for (int m = 0; m < 4; ++m) {
      #pragma unroll
      for (int j = 0; j < 4; ++j) {
        const int r = row0 + wm*64 + m*16 + hi*4 + j;
        const float v = (acc[m][n][j] + bv) * alpha;
        if (MODE == 2) {
          ((float*)out)[(size_t)r * D_ + c] = v;
        } else {
          const int bb = r >> 11, s = r & (S_ - 1);
          const int h = c >> 6, hd = c & 63;
          bf16* o = (bf16*)out;
          if (MODE == 0)
            o[((size_t)(bb * H_ + h) * S_ + s) * HD_ + hd] = (bf16)v;
          else
            o[((size_t)(bb * H_ + h) * HD_ + hd) * S_ + s] = (bf16)v;
        }
      }
    }
  }
}

// ---------------------------------------------------------------- attention
// grid (S/256, B*H); 4 waves, each owns 64 q-rows. KV tiles of 64 staged in
// LDS with rows padded to 72 bf16 (144B = 36 words -> only 2-way bank alias).
// Q pre-scaled by 1/sqrt(HD)=0.125 in the Q-GEMM epilogue (exact in bf16).
__global__ __launch_bounds__(256, 2) void attn_kernel(
    const bf16* __restrict__ q, const bf16* __restrict__ k,
    const bf16* __restrict__ vt, bf16* __restrict__ ao)
{
  __shared__ __align__(16) bf16 Kl[64 * 72];
  __shared__ __align__(16) bf16 Vl[64 * 72];       // V^T tile: rows = hd
  __shared__ __align__(16) bf16 Pl[4 * 64 * 72];   // per-wave P scratch

  const int tid = threadIdx.x;
  const int w = tid >> 6, l = tid & 63;
  const int lo = l & 15, hi = l >> 4;
  const int bh = blockIdx.y;
  const int q0 = blockIdx.x * 256 + w * 64;

  // Q fragments: A-operand, lane holds Q[row=lo][k=hi*8..+8] per 16x32 slice
  short8 aq[4][2];
  const size_t qrow = (size_t)bh * S_ + q0;
  #pragma unroll
  for (int m = 0; m < 4; ++m)
    #pragma unroll
    for (int kk = 0; kk < 2; ++kk)
      aq[m][kk] = *reinterpret_cast<const short8*>(
          q + (qrow + m*16 + lo) * HD_ + kk*32 + hi*8);

  f32x4 o[4][4] = {};
  float mrun[4][4], lrun[4][4];
  #pragma unroll
  for (int m = 0; m < 4; ++m)
    #pragma unroll
    for (int j = 0; j < 4; ++j) { mrun[m][j] = -3.0e38f; lrun[m][j] = 0.0f; }

  bf16* pw = Pl + w * (64 * 72);
  const bf16* kbase = k  + (size_t)bh * S_ * HD_;
  const bf16* vbase = vt + (size_t)bh * HD_ * S_;

  for (int kt = 0; kt < S_; kt += 64) {
    __syncthreads();   // previous tile fully consumed
    #pragma unroll
    for (int i = 0; i < 2; ++i) {
      const int c = tid + i * 256;         // 512 chunks of 16B per tile
      const int r = c >> 3, co = c & 7;
      *reinterpret_cast<int4*>(Kl + r*72 + co*8) =
          *reinterpret_cast<const int4*>(kbase + (size_t)(kt + r) * HD_ + co*8);
      *reinterpret_cast<int4*>(Vl + r*72 + co*8) =
          *reinterpret_cast<const int4*>(vbase + (size_t)r * S_ + kt + co*8);
    }
    __syncthreads();

    // S = Q @ K^T  (B-operand: col=kv from K_lds rows)
    f32x4 s[4][4] = {};
    #pragma unroll
    for (int n = 0; n < 4; ++n) {
      short8 kf0 = *reinterpret_cast<const short8*>(Kl + (n*16+lo)*72 + hi*8);
      short8 kf1 = *reinterpret_cast<const short8*>(Kl + (n*16+lo)*72 + 32 + hi*8);
      #pragma unroll
      for (int m = 0; m < 4; ++m) {
        s[m][n] = mfma16(aq[m][0], kf0, s[m][n]);
        s[m][n] = mfma16(aq[m][1], kf1, s[m][n]);
      }
    }

    // online softmax; row r = m*16 + hi*4 + j lives in the 16-lane group `hi`
    #pragma unroll
    for (int m = 0; m < 4; ++m) {
      #pragma unroll
      for (int j = 0; j < 4; ++j) {
        float mx = fmaxf(fmaxf(s[m][0][j], s[m][1][j]),
                         fmaxf(s[m][2][j], s[m][3][j]));
        #pragma unroll
        for (int d = 1; d < 16; d <<= 1) mx = fmaxf(mx, __shfl_xor(mx, d, 64));
        const float mn = fmaxf(mrun[m][j], mx);
        const float corr = __expf(mrun[m][j] - mn);
        mrun[m][j] = mn;
        float sum = 0.0f;
        #pragma unroll
        for (int n = 0; n < 4; ++n) {
          const float p = __expf(s[m][n][j] - mn);
          s[m][n][j] = p;
          sum += p;
        }
        #pragma unroll
        for (int d = 1; d < 16; d <<= 1) sum += __shfl_xor(sum, d, 64);
        lrun[m][j] = lrun[m][j] * corr + sum;
        #pragma unroll
        for (int n = 0; n < 4; ++n) o[m][n][j] *= corr;
      }
    }

    // P -> LDS (bf16) to reshape into MFMA A-fragments
    #pragma unroll
    for (int m = 0; m < 4; ++m)
      #pragma unroll
      for (int n = 0; n < 4; ++n)
        #pragma unroll
        for (int j = 0; j < 4; ++j)
          pw[(m*16 + hi*4 + j)*72 + n*16 + lo] = (bf16)s[m][n][j];
    __syncthreads();   // cross-lane LDS visibility within wave groups

    // O += P @ V   (B-operand: col=hd from V^T rows)
    short8 pa[4][2];
    #pragma unroll
    for (int m = 0; m < 4; ++m)
      #pragma unroll
      for (int kk = 0; kk < 2; ++kk)
        pa[m][kk] = *reinterpret_cast<const short8*>(pw + (m*16+lo)*72 + kk*32 + hi*8);
    #pragma unroll
    for (int n = 0; n < 4; ++n) {
      short8 vf0 = *reinterpret_cast<const short8*>(Vl + (n*16+lo)*72 + hi*8);
      short8 vf1 = *reinterpret_cast<const short8*>(Vl + (n*16+lo)*72 + 32 + hi*8);
      #pragma unroll
      for (int m = 0; m < 4; ++m) {
        o[m][n] = mfma16(pa[m][0], vf0, o[m][n]);
        o[m][n] = mfma16(pa[m][1], vf1, o[m][n]);
      }
    }
  }

  // normalize + store merged-head bf16 [b*S+s][h*64+hd]
  const int b = bh >> 4, h = bh & 15;
  #pragma unroll
  for (int m = 0; m < 4; ++m)
    #pragma unroll
    for (int j = 0; j < 4; ++j) {
      const float inv = 1.0f / lrun[m][j];
      const int srow = q0 + m*16 + hi*4 + j;
      #pragma unroll
      for (int n = 0; n < 4; ++n) {
        const int col = h*64 + n*16 + lo;
        ao[((size_t)b * S_ + srow) * D_ + col] = (bf16)(o[m][n][j] * inv);
      }
    }
}

// ---------------------------------------------------------------- launch
extern "C" void kernel_launch(void* const* d_in, const int* in_sizes, int n_in,
                              void* d_out, int out_size, void* d_ws, size_t ws_size,
                              hipStream_t stream) {
  const float* x  = (const float*)d_in[0];
  const float* wq = (const float*)d_in[1];
  const float* bq = (const float*)d_in[2];
  const float* wk = (const float*)d_in[3];
  const float* bk = (const float*)d_in[4];
  const float* wv = (const float*)d_in[5];
  const float* bv = (const float*)d_in[6];
  const float* wo = (const float*)d_in[7];
  const float* bo = (const float*)d_in[8];

  char* ws = (char*)d_ws;
  bf16* xb  = (bf16*)(ws);                           // 16 MB  x in bf16
  bf16* wqt = (bf16*)(ws + ((size_t)16 << 20));      // 2 MB   wq^T bf16
  bf16* wkt = (bf16*)(ws + ((size_t)18 << 20));
  bf16* wvt = (bf16*)(ws + ((size_t)20 << 20));
  bf16* wot = (bf16*)(ws + ((size_t)22 << 20));
  bf16* qb  = (bf16*)(ws + ((size_t)24 << 20));      // 16 MB  q [bh][s][hd]
  bf16* kb  = (bf16*)(ws + ((size_t)40 << 20));      // 16 MB  k [bh][s][hd]
  bf16* vtb = (bf16*)(ws + ((size_t)56 << 20));      // 16 MB  v^T [bh][hd][s]
  bf16* aob = (bf16*)(ws + ((size_t)72 << 20));      // 16 MB  attn out bf16

  convert_x_kernel<<<dim3((M_ * D_) / (256 * 8)), 256, 0, stream>>>(x, xb);

  TP p;
  p.w[0] = wq; p.w[1] = wk; p.w[2] = wv; p.w[3] = wo;
  p.wt[0] = wqt; p.wt[1] = wkt; p.wt[2] = wvt; p.wt[3] = wot;
  transpose_w_kernel<<<dim3(32, 32, 4), 256, 0, stream>>>(p);

  dim3 ggrid(D_ / 128, M_ / 128);   // (8, 64)
  gemm_kernel<0><<<ggrid, 256, 0, stream>>>(xb, wqt, bq, qb, 0.125f);  // Q pre-scaled
  gemm_kernel<0><<<ggrid, 256, 0, stream>>>(xb, wkt, bk, kb, 1.0f);
  gemm_kernel<1><<<ggrid, 256, 0, stream>>>(xb, wvt, bv, vtb, 1.0f);

  attn_kernel<<<dim3(S_ / 256, B_ * H_), 256, 0, stream>>>(qb, kb, vtb, aob);

  gemm_kernel<2><<<ggrid, 256, 0, stream>>>(aob, wot, bo, d_out, 1.0f);
}

// Round 2
// 323.809 us; speedup vs baseline: 1.4323x; 1.4323x over previous
//
#include <hip/hip_runtime.h>
#include <hip/hip_bf16.h>

// MultiHeadSelfAttention: B=4, S=2048, D=1024, H=16, HD=64, fp32 in/out.
// bf16 MFMA GEMMs (m97 128x128 structure) + flash attention with swapped
// QK^T (S^T = K@Q^T) so softmax is q-local and P packs in-register into
// the PV B-operand (no P LDS round-trip). O accumulated transposed.

#define B_  4
#define S_  2048
#define D_  1024
#define H_  16
#define HD_ 64
#define M_  (B_*S_)   // 8192 rows

typedef __attribute__((ext_vector_type(8))) short short8;   // 8 x bf16 (4 VGPR)
typedef __attribute__((ext_vector_type(4))) float f32x4;    // MFMA acc
typedef __hip_bfloat16 bf16;

// ---------------------------------------------------------------- helpers
__device__ inline void gload_lds16(const void* g, void* l) {
  __builtin_amdgcn_global_load_lds(
      (const __attribute__((address_space(1))) void*)g,
      (__attribute__((address_space(3))) void*)l,
      16, 0, 0);
}

__device__ inline f32x4 mfma16(short8 a, short8 b, f32x4 c) {
  return __builtin_amdgcn_mfma_f32_16x16x32_bf16(a, b, c, 0, 0, 0);
}

__device__ inline short bfbits(float f) {
  bf16 h = (bf16)f;
  return *reinterpret_cast<short*>(&h);
}

// ---------------------------------------------------------------- convert x
__global__ void convert_x_kernel(const float* __restrict__ x, bf16* __restrict__ xb) {
  const int i = (blockIdx.x * 256 + threadIdx.x) * 8;
  float4 a = *reinterpret_cast<const float4*>(x + i);
  float4 b = *reinterpret_cast<const float4*>(x + i + 4);
  bf16 o[8];
  o[0] = (bf16)a.x; o[1] = (bf16)a.y; o[2] = (bf16)a.z; o[3] = (bf16)a.w;
  o[4] = (bf16)b.x; o[5] = (bf16)b.y; o[6] = (bf16)b.z; o[7] = (bf16)b.w;
  *reinterpret_cast<int4*>(xb + i) = *reinterpret_cast<const int4*>(o);
}

// ------------------------------------------------- transpose + convert weights
struct TP { const float* w[4]; bf16* wt[4]; };

__global__ void transpose_w_kernel(TP p) {
  const float* w = p.w[blockIdx.z];
  bf16* wt = p.wt[blockIdx.z];
  __shared__ float t[32][33];
  const int k0 = blockIdx.y * 32, n0 = blockIdx.x * 32;
  const int c = threadIdx.x & 31, r4 = threadIdx.x >> 5;
  #pragma unroll
  for (int i = 0; i < 4; ++i) {
    int r = r4 + i * 8;
    t[r][c] = w[(size_t)(k0 + r) * D_ + n0 + c];
  }
  __syncthreads();
  #pragma unroll
  for (int i = 0; i < 4; ++i) {
    int r = r4 + i * 8;
    wt[(size_t)(n0 + r) * D_ + k0 + c] = (bf16)t[c][r];
  }
}

// ---------------------------------------------------------------- GEMM
// C[M,N] = A[M,K] @ Bt[N,K]^T + bias, 128x128 tile, BK=32, 4 waves (2x2).
// MODE 0: bf16 out, head-split [bh][s][hd]   (q / k)
// MODE 1: bf16 out, head-split T [bh][hd][s] (v transposed)
// MODE 2: fp32 out, plain [r][c]             (final projection)
template<int MODE>
__global__ __launch_bounds__(256) void gemm_kernel(
    const bf16* __restrict__ A, const bf16* __restrict__ Bt,
    const float* __restrict__ bias, void* __restrict__ out, float alpha)
{
  constexpr int BK = 32;
  __shared__ __align__(16) bf16 As[128 * BK];
  __shared__ __align__(16) bf16 Bs[128 * BK];
  const int tid = threadIdx.x;
  const int w = tid >> 6, l = tid & 63;
  const int lo = l & 15, hi = l >> 4;
  const int wm = w >> 1, wn = w & 1;
  const int row0 = blockIdx.y * 128;
  const int col0 = blockIdx.x * 128;

  f32x4 acc[4][4] = {};

  for (int kt = 0; kt < D_; kt += BK) {
    __syncthreads();
    #pragma unroll
    for (int i = 0; i < 2; ++i) {
      const int cb = i * 256 + w * 64;
      const int c  = cb + l;
      gload_lds16(A  + (size_t)(row0 + (c >> 2)) * D_ + kt + (c & 3) * 8,
                  (void*)(As + cb * 8));
      gload_lds16(Bt + (size_t)(col0 + (c >> 2)) * D_ + kt + (c & 3) * 8,
                  (void*)(Bs + cb * 8));
    }
    __syncthreads();

    short8 a[4], b[4];
    #pragma unroll
    for (int m = 0; m < 4; ++m)
      a[m] = *reinterpret_cast<const short8*>(As + (wm*64 + m*16 + lo) * BK + hi*8);
    #pragma unroll
    for (int n = 0; n < 4; ++n)
      b[n] = *reinterpret_cast<const short8*>(Bs + (wn*64 + n*16 + lo) * BK + hi*8);
    #pragma unroll
    for (int m = 0; m < 4; ++m)
      #pragma unroll
      for (int n = 0; n < 4; ++n)
        acc[m][n] = mfma16(a[m], b[n], acc[m][n]);
  }

  #pragma unroll
  for (int n = 0; n < 4; ++n) {
    const int c = col0 + wn*64 + n*16 + lo;
    const float bv = bias[c];
    #pragma unroll
    for (int m = 0; m < 4; ++m) {
      #pragma unroll
      for (int j = 0; j < 4; ++j) {
        const int r = row0 + wm*64 + m*16 + hi*4 + j;
        const float v = (acc[m][n][j] + bv) * alpha;
        if (MODE == 2) {
          ((float*)out)[(size_t)r * D_ + c] = v;
        } else {
          const int bb = r >> 11, s = r & (S_ - 1);
          const int h = c >> 6, hd = c & 63;
          bf16* o = (bf16*)out;
          if (MODE == 0)
            o[((size_t)(bb * H_ + h) * S_ + s) * HD_ + hd] = (bf16)v;
          else
            o[((size_t)(bb * H_ + h) * HD_ + hd) * S_ + s] = (bf16)v;
        }
      }
    }
  }
}

// ---------------------------------------------------------------- attention
// grid (S/256, B*H); 4 waves, each owns 64 q-rows. KV tiles of 64 in LDS
// (rows padded to 72 bf16 -> only 2-way bank alias).
// Swapped QK^T: s[m][n] = mfma(A=K-frag m, B=Q-frag n) gives
//   S^T[kv = m*16 + hi*4 + j][q = n*16 + lo]  (q is lane-local in lo).
// PV accumulates O^T[hd][q] = mfma(A=V^T-frag, B=P^T packed in-register);
// per-hi-group k-slot order is {hi*4+j, 16+hi*4+j} per 32-slice, consistent
// between the V A-operand (two b64 LDS reads) and the packed P B-operand.
__global__ __launch_bounds__(256, 2) void attn_kernel(
    const bf16* __restrict__ q, const bf16* __restrict__ k,
    const bf16* __restrict__ vt, bf16* __restrict__ ao)
{
  __shared__ __align__(16) bf16 Kl[64 * 72];
  __shared__ __align__(16) bf16 Vtl[64 * 72];   // V^T tile: rows = hd

  const int tid = threadIdx.x;
  const int w = tid >> 6, l = tid & 63;
  const int lo = l & 15, hi = l >> 4;
  const int bh = blockIdx.y;
  const int q0 = blockIdx.x * 256 + w * 64;

  const bf16* kbase = k  + (size_t)bh * S_ * HD_;
  const bf16* vbase = vt + (size_t)bh * HD_ * S_;

  // Q B-frags: lane holds Q[q = n*16+lo][hd = kk*32 + hi*8 .. +8]
  short8 bq[4][2];
  const size_t qrow = (size_t)bh * S_ + q0;
  #pragma unroll
  for (int n = 0; n < 4; ++n)
    #pragma unroll
    for (int kk = 0; kk < 2; ++kk)
      bq[n][kk] = *reinterpret_cast<const short8*>(
          q + (qrow + n*16 + lo) * HD_ + kk*32 + hi*8);

  f32x4 o[4][4] = {};        // o[mm = hd-frag][n = q-frag]
  float mrun[4], lrun[4];
  #pragma unroll
  for (int n = 0; n < 4; ++n) { mrun[n] = -3.0e38f; lrun[n] = 0.0f; }

  // staging: 512 x 16B chunks per tile, 2 per thread
  const int r0 = tid >> 3,        co0 = (tid & 7) * 8;
  const int r1 = (tid + 256) >> 3, co1 = (tid & 7) * 8;

  // T14 async-STAGE split: prefetch tile kt+64 into regs before compute(kt)
  int4 kreg0, kreg1, vreg0, vreg1;
  kreg0 = *reinterpret_cast<const int4*>(kbase + (size_t)r0 * HD_ + co0);
  kreg1 = *reinterpret_cast<const int4*>(kbase + (size_t)r1 * HD_ + co1);
  vreg0 = *reinterpret_cast<const int4*>(vbase + (size_t)r0 * S_ + co0);
  vreg1 = *reinterpret_cast<const int4*>(vbase + (size_t)r1 * S_ + co1);

  for (int kt = 0; kt < S_; kt += 64) {
    __syncthreads();   // previous tile fully consumed
    *reinterpret_cast<int4*>(Kl  + r0*72 + co0) = kreg0;
    *reinterpret_cast<int4*>(Kl  + r1*72 + co1) = kreg1;
    *reinterpret_cast<int4*>(Vtl + r0*72 + co0) = vreg0;
    *reinterpret_cast<int4*>(Vtl + r1*72 + co1) = vreg1;
    if (kt + 64 < S_) {
      const int nt = kt + 64;
      kreg0 = *reinterpret_cast<const int4*>(kbase + (size_t)(nt + r0) * HD_ + co0);
      kreg1 = *reinterpret_cast<const int4*>(kbase + (size_t)(nt + r1) * HD_ + co1);
      vreg0 = *reinterpret_cast<const int4*>(vbase + (size_t)r0 * S_ + nt + co0);
      vreg1 = *reinterpret_cast<const int4*>(vbase + (size_t)r1 * S_ + nt + co1);
    }
    __syncthreads();

    // S^T = K @ Q^T
    f32x4 s[4][4] = {};
    __builtin_amdgcn_s_setprio(1);
    #pragma unroll
    for (int m = 0; m < 4; ++m) {
      short8 kf0 = *reinterpret_cast<const short8*>(Kl + (m*16+lo)*72 + hi*8);
      short8 kf1 = *reinterpret_cast<const short8*>(Kl + (m*16+lo)*72 + 32 + hi*8);
      #pragma unroll
      for (int n = 0; n < 4; ++n) {
        s[m][n] = mfma16(kf0, bq[n][0], s[m][n]);
        s[m][n] = mfma16(kf1, bq[n][1], s[m][n]);
      }
    }
    __builtin_amdgcn_s_setprio(0);

    // online softmax per q = n*16+lo (16 in-lane values + 2 shfl)
    short8 pb[4][2];
    #pragma unroll
    for (int n = 0; n < 4; ++n) {
      float mx = fmaxf(
          fmaxf(fmaxf(fmaxf(s[0][n][0], s[0][n][1]), fmaxf(s[0][n][2], s[0][n][3])),
                fmaxf(fmaxf(s[1][n][0], s[1][n][1]), fmaxf(s[1][n][2], s[1][n][3]))),
          fmaxf(fmaxf(fmaxf(s[2][n][0], s[2][n][1]), fmaxf(s[2][n][2], s[2][n][3])),
                fmaxf(fmaxf(s[3][n][0], s[3][n][1]), fmaxf(s[3][n][2], s[3][n][3]))));
      mx = fmaxf(mx, __shfl_xor(mx, 16, 64));
      mx = fmaxf(mx, __shfl_xor(mx, 32, 64));
      const float mn = fmaxf(mrun[n], mx);
      const float corr = __expf(mrun[n] - mn);
      mrun[n] = mn;
      float sum = 0.0f;
      #pragma unroll
      for (int m = 0; m < 4; ++m)
        #pragma unroll
        for (int j = 0; j < 4; ++j) {
          const float p = __expf(s[m][n][j] - mn);
          s[m][n][j] = p;
          sum += p;
        }
      sum += __shfl_xor(sum, 16, 64);
      sum += __shfl_xor(sum, 32, 64);
      lrun[n] = lrun[n] * corr + sum;
      #pragma unroll
      for (int mm = 0; mm < 4; ++mm)
        #pragma unroll
        for (int j = 0; j < 4; ++j)
          o[mm][n][j] *= corr;
      // pack P^T into PV B-operand: slice kk from S^T frags m=2kk, 2kk+1
      #pragma unroll
      for (int kk = 0; kk < 2; ++kk) {
        short8 t;
        t[0] = bfbits(s[2*kk][n][0]);   t[1] = bfbits(s[2*kk][n][1]);
        t[2] = bfbits(s[2*kk][n][2]);   t[3] = bfbits(s[2*kk][n][3]);
        t[4] = bfbits(s[2*kk+1][n][0]); t[5] = bfbits(s[2*kk+1][n][1]);
        t[6] = bfbits(s[2*kk+1][n][2]); t[7] = bfbits(s[2*kk+1][n][3]);
        pb[n][kk] = t;
      }
    }

    // O^T += V^T @ P^T  (A = V^T frag: two b64 reads at kv offsets matching
    // the packed P k-slot order)
    __builtin_amdgcn_s_setprio(1);
    #pragma unroll
    for (int mm = 0; mm < 4; ++mm) {
      short8 vf[2];
      #pragma unroll
      for (int kk = 0; kk < 2; ++kk) {
        union { short8 v; uint2 u2[2]; } x;
        x.u2[0] = *reinterpret_cast<const uint2*>(Vtl + (mm*16+lo)*72 + kk*32 + hi*4);
        x.u2[1] = *reinterpret_cast<const uint2*>(Vtl + (mm*16+lo)*72 + kk*32 + 16 + hi*4);
        vf[kk] = x.v;
      }
      #pragma unroll
      for (int n = 0; n < 4; ++n) {
        o[mm][n] = mfma16(vf[0], pb[n][0], o[mm][n]);
        o[mm][n] = mfma16(vf[1], pb[n][1], o[mm][n]);
      }
    }
    __builtin_amdgcn_s_setprio(0);
  }

  // normalize + store O^T -> merged-head bf16 [b*S+s][h*64+hd]
  const int b = bh >> 4, h = bh & 15;
  #pragma unroll
  for (int n = 0; n < 4; ++n) {
    const float inv = 1.0f / lrun[n];
    const size_t row = (size_t)b * S_ + q0 + n*16 + lo;
    #pragma unroll
    for (int mm = 0; mm < 4; ++mm) {
      bf16 ov[4];
      #pragma unroll
      for (int j = 0; j < 4; ++j) ov[j] = (bf16)(o[mm][n][j] * inv);
      *reinterpret_cast<uint2*>(ao + row * D_ + h*64 + mm*16 + hi*4) =
          *reinterpret_cast<const uint2*>(ov);
    }
  }
}

// ---------------------------------------------------------------- launch
extern "C" void kernel_launch(void* const* d_in, const int* in_sizes, int n_in,
                              void* d_out, int out_size, void* d_ws, size_t ws_size,
                              hipStream_t stream) {
  const float* x  = (const float*)d_in[0];
  const float* wq = (const float*)d_in[1];
  const float* bq = (const float*)d_in[2];
  const float* wk = (const float*)d_in[3];
  const float* bk = (const float*)d_in[4];
  const float* wv = (const float*)d_in[5];
  const float* bv = (const float*)d_in[6];
  const float* wo = (const float*)d_in[7];
  const float* bo = (const float*)d_in[8];

  char* ws = (char*)d_ws;
  bf16* xb  = (bf16*)(ws);                           // 16 MB  x in bf16
  bf16* wqt = (bf16*)(ws + ((size_t)16 << 20));      // 2 MB   wq^T bf16
  bf16* wkt = (bf16*)(ws + ((size_t)18 << 20));
  bf16* wvt = (bf16*)(ws + ((size_t)20 << 20));
  bf16* wot = (bf16*)(ws + ((size_t)22 << 20));
  bf16* qb  = (bf16*)(ws + ((size_t)24 << 20));      // 16 MB  q [bh][s][hd]
  bf16* kb  = (bf16*)(ws + ((size_t)40 << 20));      // 16 MB  k [bh][s][hd]
  bf16* vtb = (bf16*)(ws + ((size_t)56 << 20));      // 16 MB  v^T [bh][hd][s]
  bf16* aob = (bf16*)(ws + ((size_t)72 << 20));      // 16 MB  attn out bf16

  convert_x_kernel<<<dim3((M_ * D_) / (256 * 8)), 256, 0, stream>>>(x, xb);

  TP p;
  p.w[0] = wq; p.w[1] = wk; p.w[2] = wv; p.w[3] = wo;
  p.wt[0] = wqt; p.wt[1] = wkt; p.wt[2] = wvt; p.wt[3] = wot;
  transpose_w_kernel<<<dim3(32, 32, 4), 256, 0, stream>>>(p);

  dim3 ggrid(D_ / 128, M_ / 128);   // (8, 64)
  gemm_kernel<0><<<ggrid, 256, 0, stream>>>(xb, wqt, bq, qb, 0.125f);  // Q pre-scaled
  gemm_kernel<0><<<ggrid, 256, 0, stream>>>(xb, wkt, bk, kb, 1.0f);
  gemm_kernel<1><<<ggrid, 256, 0, stream>>>(xb, wvt, bv, vtb, 1.0f);

  attn_kernel<<<dim3(S_ / 256, B_ * H_), 256, 0, stream>>>(qb, kb, vtb, aob);

  gemm_kernel<2><<<ggrid, 256, 0, stream>>>(aob, wot, bo, d_out, 1.0f);
}